// Round 1
// baseline (177.945 us; speedup 1.0000x reference)
//
#include <hip/hip_runtime.h>
#include <stdint.h>

// Sparse top-k attention, B=1 S=2048 H=16 D=128 N_KV=8192 K=512.
// One block per query position; 4 waves x 128 private keys; bf16 MFMA 16x16x32.
// No __syncthreads in the key loop (wave-private LDS tiles); 2 barriers total.

typedef float  f32x4 __attribute__((ext_vector_type(4)));
typedef short  s16x8 __attribute__((ext_vector_type(8)));

#define S_LEN   2048
#define N_HEADS 16
#define D_HEAD  128
#define TOPK    512

// fp32 -> bf16 round-nearest-even
__device__ __forceinline__ unsigned short f2bf(float f) {
  union { float f; unsigned u; } v; v.f = f;
  return (unsigned short)((v.u + 0x7fffu + ((v.u >> 16) & 1u)) >> 16);
}

// LDS map (bytes):
//  [0,36864)      kv tiles: wave w at w*9216, 32 rows x 144 ushort (288 B/row)
//                 (after key loop, overlapped by o_lds [4][16][132] fp32 = 33792 B)
//  [36864,41984)  p tiles: wave w at +w*1280, 16 rows x 40 ushort (80 B/row)
//  [41984,42496)  bias [4][32] fp32
//  [42496,42752)  m [4][16] fp32
//  [42752,43008)  l [4][16] fp32
//  [43008,43072)  L [16] fp32
#define SMEM_BYTES 43072

__global__ void __launch_bounds__(256) g2core_sparse_attn(
    const float* __restrict__ qg, const float* __restrict__ kvg,
    const int* __restrict__ tkg, float* __restrict__ outg) {
  __shared__ __align__(16) char smem[SMEM_BYTES];
  unsigned short* kv_all  = (unsigned short*)smem;
  float*          o_all   = (float*)smem;                    // union w/ kv (post-loop)
  unsigned short* p_all   = (unsigned short*)(smem + 36864);
  float*          bias_all= (float*)(smem + 41984);
  float*          m_lds   = (float*)(smem + 42496);
  float*          l_lds   = (float*)(smem + 42752);
  float*          L_lds   = (float*)(smem + 43008);

  const int s    = blockIdx.x;
  const int tid  = threadIdx.x;
  const int wave = tid >> 6;
  const int lane = tid & 63;
  const int quad = lane >> 4;   // 0..3
  const int n16  = lane & 15;   // 0..15

  unsigned short* kvw   = kv_all + wave * 4608;   // 32 x 144 ushorts
  unsigned short* pw    = p_all  + wave * 640;    // 16 x 40 ushorts
  float*          biasw = bias_all + wave * 32;

  // fold 1/sqrt(128) * log2(e) into Q so softmax runs in exp2 domain
  const float QSCALE = 0.08838834764831845f * 1.4426950408889634f;

  // ---- Q A-frags in registers: A[m=n16(head)][k=32c+8*quad+j] ----
  s16x8 qf[4];
  {
    const float* qrow = qg + ((size_t)s * N_HEADS + n16) * D_HEAD;
#pragma unroll
    for (int c = 0; c < 4; ++c) {
      const float* p0 = qrow + c * 32 + quad * 8;
      float4 a = *(const float4*)(p0);
      float4 b = *(const float4*)(p0 + 4);
      s16x8 f;
      f[0] = (short)f2bf(a.x * QSCALE); f[1] = (short)f2bf(a.y * QSCALE);
      f[2] = (short)f2bf(a.z * QSCALE); f[3] = (short)f2bf(a.w * QSCALE);
      f[4] = (short)f2bf(b.x * QSCALE); f[5] = (short)f2bf(b.y * QSCALE);
      f[6] = (short)f2bf(b.z * QSCALE); f[7] = (short)f2bf(b.w * QSCALE);
      qf[c] = f;
    }
  }

  f32x4 o_acc[8];
#pragma unroll
  for (int t = 0; t < 8; ++t) o_acc[t] = (f32x4){0.f, 0.f, 0.f, 0.f};
  float m_r[4] = {-1e30f, -1e30f, -1e30f, -1e30f};
  float l_r[4] = {0.f, 0.f, 0.f, 0.f};

  const int* tk_base = tkg + (size_t)s * TOPK + wave * 128;

  // ================= key loop: 4 tiles x 32 keys, wave-private =================
  for (int t = 0; t < 4; ++t) {
    const int* tk = tk_base + t * 32;

    // ---- gather 32 rows fp32 -> bf16 into kvw (8 lanes/row, 128 B segments) ----
#pragma unroll
    for (int it = 0; it < 4; ++it) {
      int rl = it * 8 + (lane >> 3);
      int ki = tk[rl];
      const float* src = kvg + (size_t)(ki < 0 ? 0 : ki) * D_HEAD + (lane & 7) * 4;
      unsigned short* dst = kvw + rl * 144 + (lane & 7) * 4;
#pragma unroll
      for (int j = 0; j < 4; ++j) {
        float4 v = *(const float4*)(src + 32 * j);
        unsigned lo = (unsigned)f2bf(v.x) | ((unsigned)f2bf(v.y) << 16);
        unsigned hi = (unsigned)f2bf(v.z) | ((unsigned)f2bf(v.w) << 16);
        *(uint2*)(dst + 32 * j) = make_uint2(lo, hi);
      }
    }
    if (lane < 32) {
      int ki = tk[lane];
      biasw[lane] = (ki < 0) ? -30000.0f : 0.0f;   // masked -> p underflows to 0
    }

    // ---- QK: S[h][k] = Q*K^T, 2 n-tiles x 4 K-chunks ----
    float sv[2][4];
#pragma unroll
    for (int nt = 0; nt < 2; ++nt) {
      f32x4 sa = (f32x4){0.f, 0.f, 0.f, 0.f};
#pragma unroll
      for (int c = 0; c < 4; ++c) {
        s16x8 bf = *(const s16x8*)(kvw + (nt * 16 + n16) * 144 + c * 32 + quad * 8);
        sa = __builtin_amdgcn_mfma_f32_16x16x32_bf16(qf[c], bf, sa, 0, 0, 0);
      }
      float bias = biasw[nt * 16 + n16];
#pragma unroll
      for (int r = 0; r < 4; ++r) sv[nt][r] = sa[r] + bias;
    }

    // ---- online softmax (exp2 domain); rows live in-lane, cols across 16 lanes ----
    float mt[4];
#pragma unroll
    for (int r = 0; r < 4; ++r) mt[r] = fmaxf(sv[0][r], sv[1][r]);
#pragma unroll
    for (int msk = 1; msk <= 8; msk <<= 1)
#pragma unroll
      for (int r = 0; r < 4; ++r) mt[r] = fmaxf(mt[r], __shfl_xor(mt[r], msk));

    float al[4];
#pragma unroll
    for (int r = 0; r < 4; ++r) {
      float mn = fmaxf(m_r[r], mt[r]);
      al[r] = exp2f(m_r[r] - mn);
      m_r[r] = mn;
    }
    float pv[2][4];
#pragma unroll
    for (int nt = 0; nt < 2; ++nt)
#pragma unroll
      for (int r = 0; r < 4; ++r) pv[nt][r] = exp2f(sv[nt][r] - m_r[r]);
    float ps[4];
#pragma unroll
    for (int r = 0; r < 4; ++r) ps[r] = pv[0][r] + pv[1][r];
#pragma unroll
    for (int msk = 1; msk <= 8; msk <<= 1)
#pragma unroll
      for (int r = 0; r < 4; ++r) ps[r] += __shfl_xor(ps[r], msk);
#pragma unroll
    for (int r = 0; r < 4; ++r) l_r[r] = l_r[r] * al[r] + ps[r];
#pragma unroll
    for (int dt = 0; dt < 8; ++dt)
#pragma unroll
      for (int r = 0; r < 4; ++r) o_acc[dt][r] *= al[r];

    // ---- P transpose through LDS: C-layout -> A-layout ----
#pragma unroll
    for (int nt = 0; nt < 2; ++nt)
#pragma unroll
      for (int r = 0; r < 4; ++r)
        pw[(quad * 4 + r) * 40 + nt * 16 + n16] = f2bf(pv[nt][r]);

    // ---- PV: O[h][d] += P*V ; A-frag from pw (b128), V B-frags strided u16 ----
    s16x8 pf = *(const s16x8*)(pw + n16 * 40 + quad * 8);
#pragma unroll
    for (int dt = 0; dt < 8; ++dt) {
      const unsigned short* colp = kvw + (quad * 8) * 144 + dt * 16 + n16;
      s16x8 vf;
#pragma unroll
      for (int j = 0; j < 8; ++j) vf[j] = (short)colp[j * 144];
      o_acc[dt] = __builtin_amdgcn_mfma_f32_16x16x32_bf16(pf, vf, o_acc[dt], 0, 0, 0);
    }
  }

  // ================= cross-wave combine (2 barriers total) =================
  if (n16 == 0) {
#pragma unroll
    for (int r = 0; r < 4; ++r) {
      m_lds[wave * 16 + quad * 4 + r] = m_r[r];
      l_lds[wave * 16 + quad * 4 + r] = l_r[r];
    }
  }
  __syncthreads();

  float myscale[4];
#pragma unroll
  for (int r = 0; r < 4; ++r) {
    int h = quad * 4 + r;
    float m0 = m_lds[h], m1 = m_lds[16 + h], m2 = m_lds[32 + h], m3 = m_lds[48 + h];
    float Mx = fmaxf(fmaxf(m0, m1), fmaxf(m2, m3));
    float Ls = l_lds[h] * exp2f(m0 - Mx) + l_lds[16 + h] * exp2f(m1 - Mx)
             + l_lds[32 + h] * exp2f(m2 - Mx) + l_lds[48 + h] * exp2f(m3 - Mx);
    myscale[r] = exp2f(m_r[r] - Mx);
    if (wave == 0 && n16 == 0) L_lds[h] = Ls;
  }
  // scaled partial O into LDS (overlaps kv region; all waves past key loop here)
#pragma unroll
  for (int dt = 0; dt < 8; ++dt)
#pragma unroll
    for (int r = 0; r < 4; ++r)
      o_all[(wave * 16 + quad * 4 + r) * 132 + dt * 16 + n16] = o_acc[dt][r] * myscale[r];
  __syncthreads();

  // final reduce over 4 waves + normalize; coalesced store
  float* outp = outg + (size_t)s * (N_HEADS * D_HEAD);
#pragma unroll
  for (int i = 0; i < 8; ++i) {
    int e = i * 256 + tid;           // 0..2047
    int h = e >> 7, d = e & 127;
    float acc = o_all[(0 * 16 + h) * 132 + d] + o_all[(1 * 16 + h) * 132 + d]
              + o_all[(2 * 16 + h) * 132 + d] + o_all[(3 * 16 + h) * 132 + d];
    outp[e] = acc / L_lds[h];
  }
}

extern "C" void kernel_launch(void* const* d_in, const int* in_sizes, int n_in,
                              void* d_out, int out_size, void* d_ws, size_t ws_size,
                              hipStream_t stream) {
  const float* q    = (const float*)d_in[0];
  const float* kv   = (const float*)d_in[1];
  const int*   topk = (const int*)d_in[2];
  float*       out  = (float*)d_out;
  g2core_sparse_attn<<<dim3(S_LEN), dim3(256), 0, stream>>>(q, kv, topk, out);
}

// Round 2
// 118.941 us; speedup vs baseline: 1.4961x; 1.4961x over previous
//
#include <hip/hip_runtime.h>
#include <stdint.h>

// Sparse top-k attention, B=1 S=2048 H=16 D=128 N_KV=8192 K=512.
// R2: bf16 KV pre-convert (d_ws) + global_load_lds DMA gather with scalar
// indices + bank-skewed KV layout (V-frag reads conflict-free). One block per
// query position; 4 waves x 128 private keys; no barriers in the key loop.

typedef float  f32x4 __attribute__((ext_vector_type(4)));
typedef short  s16x8 __attribute__((ext_vector_type(8)));

#define S_LEN   2048
#define N_HEADS 16
#define D_HEAD  128
#define TOPK    512

// LDS map (bytes):
//  [0,35200)       kv tiles: wave w at w*8800; row r at (r>>3)*2208+(r&7)*272
//                  (+32B skew per 8-row group de-conflicts V column reads;
//                   row data 256B bf16, DMA-written contiguous)
//                  (after key loop, overlapped by o_lds [4][16][132] f32 = 33792B)
//  [35200,40320)   p tiles: wave w at +w*1280, 16 rows x 40 ushort
//  [40320,40576)   m [4][16] f32
//  [40576,40832)   l [4][16] f32
//  [40832,40896)   L [16] f32
#define KV_WAVE  8800
#define P_BASE   35200
#define P_WAVE   1280
#define M_BASE   40320
#define L_BASE   40576
#define LF_BASE  40832
#define SMEM_BYTES 40896
#define KVROW(r) ((((r) >> 3) * 2208) + (((r) & 7) * 272))

// fp32 -> bf16 round-nearest-even
__device__ __forceinline__ unsigned short f2bf(float f) {
  union { float f; unsigned u; } v; v.f = f;
  return (unsigned short)((v.u + 0x7fffu + ((v.u >> 16) & 1u)) >> 16);
}

__global__ void __launch_bounds__(256) kv_cvt_bf16(
    const float* __restrict__ kv, unsigned short* __restrict__ o) {
  int i = (blockIdx.x * 256 + threadIdx.x) * 8;   // 8192*128 = 1M elems, grid 512
  float4 a = *(const float4*)(kv + i);
  float4 b = *(const float4*)(kv + i + 4);
  uint4 p;
  p.x = (unsigned)f2bf(a.x) | ((unsigned)f2bf(a.y) << 16);
  p.y = (unsigned)f2bf(a.z) | ((unsigned)f2bf(a.w) << 16);
  p.z = (unsigned)f2bf(b.x) | ((unsigned)f2bf(b.y) << 16);
  p.w = (unsigned)f2bf(b.z) | ((unsigned)f2bf(b.w) << 16);
  *(uint4*)(o + i) = p;
}

__global__ void __launch_bounds__(256) g2core_sparse_attn(
    const float* __restrict__ qg, const unsigned short* __restrict__ kvb,
    const int* __restrict__ tkg, float* __restrict__ outg) {
  __shared__ __align__(16) char smem[SMEM_BYTES];
  float*          o_all = (float*)smem;                    // union w/ kv (post-loop)
  unsigned short* p_all = (unsigned short*)(smem + P_BASE);
  float*          m_lds = (float*)(smem + M_BASE);
  float*          l_lds = (float*)(smem + L_BASE);
  float*          L_lds = (float*)(smem + LF_BASE);

  const int s    = blockIdx.x;
  const int tid  = threadIdx.x;
  const int wave = __builtin_amdgcn_readfirstlane(tid >> 6);  // force wave-uniform
  const int lane = tid & 63;
  const int quad = lane >> 4;   // 0..3
  const int n16  = lane & 15;   // 0..15

  char*           kvw_b = smem + wave * KV_WAVE;
  unsigned short* pw    = p_all + wave * (P_WAVE / 2);

  // fold 1/sqrt(128) * log2(e) into Q so softmax runs in exp2 domain
  const float QSCALE = 0.08838834764831845f * 1.4426950408889634f;

  // ---- Q A-frags in registers: A[m=n16(head)][k=32c+8*quad+j] ----
  s16x8 qf[4];
  {
    const float* qrow = qg + ((size_t)s * N_HEADS + n16) * D_HEAD;
#pragma unroll
    for (int c = 0; c < 4; ++c) {
      const float* p0 = qrow + c * 32 + quad * 8;
      float4 a = *(const float4*)(p0);
      float4 b = *(const float4*)(p0 + 4);
      s16x8 f;
      f[0] = (short)f2bf(a.x * QSCALE); f[1] = (short)f2bf(a.y * QSCALE);
      f[2] = (short)f2bf(a.z * QSCALE); f[3] = (short)f2bf(a.w * QSCALE);
      f[4] = (short)f2bf(b.x * QSCALE); f[5] = (short)f2bf(b.y * QSCALE);
      f[6] = (short)f2bf(b.z * QSCALE); f[7] = (short)f2bf(b.w * QSCALE);
      qf[c] = f;
    }
  }

  f32x4 o_acc[8];
#pragma unroll
  for (int t = 0; t < 8; ++t) o_acc[t] = (f32x4){0.f, 0.f, 0.f, 0.f};
  float m_r[4] = {-1e30f, -1e30f, -1e30f, -1e30f};
  float l_r[4] = {0.f, 0.f, 0.f, 0.f};

  const int* tk_base = tkg + (size_t)s * TOPK + wave * 128;

  // ================= key loop: 4 tiles x 32 keys, wave-private =================
  for (int t = 0; t < 4; ++t) {
    const int* tk = tk_base + t * 32;   // uniform pointer -> scalar index loads

    // ---- gather: 32 rows via global_load_lds DMA (256B bf16/row) ----
    unsigned vmask = 0;
#pragma unroll
    for (int r = 0; r < 32; ++r) {
      int ki = tk[r];
      vmask |= (unsigned)(ki < 0) << r;
      ki = ki < 0 ? 0 : ki;
      const unsigned int* src = (const unsigned int*)kvb + (size_t)ki * 64 + lane;
      unsigned int* dst = (unsigned int*)(kvw_b + KVROW(r));
      __builtin_amdgcn_global_load_lds(
          (const __attribute__((address_space(1))) unsigned int*)src,
          (__attribute__((address_space(3))) unsigned int*)dst, 4, 0, 0);
    }
    __builtin_amdgcn_s_waitcnt(0x0F70);   // vmcnt(0): DMA landed (wave-private, no barrier)

    // ---- QK: S[h][k] = Q*K^T ----
    float sv[2][4];
#pragma unroll
    for (int nt = 0; nt < 2; ++nt) {
      const char* krow = kvw_b + (nt * 2 + (n16 >> 3)) * 2208 + (n16 & 7) * 272;
      f32x4 sa = (f32x4){0.f, 0.f, 0.f, 0.f};
#pragma unroll
      for (int c = 0; c < 4; ++c) {
        s16x8 bf = *(const s16x8*)(krow + c * 64 + quad * 16);
        sa = __builtin_amdgcn_mfma_f32_16x16x32_bf16(qf[c], bf, sa, 0, 0, 0);
      }
      float bias = ((vmask >> (nt * 16 + n16)) & 1u) ? -30000.0f : 0.0f;
#pragma unroll
      for (int r = 0; r < 4; ++r) sv[nt][r] = sa[r] + bias;
    }

    // ---- online softmax (exp2 domain); rows in-lane, cols across 16 lanes ----
    float mt[4];
#pragma unroll
    for (int r = 0; r < 4; ++r) mt[r] = fmaxf(sv[0][r], sv[1][r]);
#pragma unroll
    for (int msk = 1; msk <= 8; msk <<= 1)
#pragma unroll
      for (int r = 0; r < 4; ++r) mt[r] = fmaxf(mt[r], __shfl_xor(mt[r], msk));

    float al[4];
#pragma unroll
    for (int r = 0; r < 4; ++r) {
      float mn = fmaxf(m_r[r], mt[r]);
      al[r] = exp2f(m_r[r] - mn);
      m_r[r] = mn;
    }
    float pv[2][4];
#pragma unroll
    for (int nt = 0; nt < 2; ++nt)
#pragma unroll
      for (int r = 0; r < 4; ++r) pv[nt][r] = exp2f(sv[nt][r] - m_r[r]);
    float ps[4];
#pragma unroll
    for (int r = 0; r < 4; ++r) ps[r] = pv[0][r] + pv[1][r];
#pragma unroll
    for (int msk = 1; msk <= 8; msk <<= 1)
#pragma unroll
      for (int r = 0; r < 4; ++r) ps[r] += __shfl_xor(ps[r], msk);
#pragma unroll
    for (int r = 0; r < 4; ++r) l_r[r] = l_r[r] * al[r] + ps[r];
#pragma unroll
    for (int dt = 0; dt < 8; ++dt)
#pragma unroll
      for (int r = 0; r < 4; ++r) o_acc[dt][r] *= al[r];

    // ---- P transpose through LDS: C-layout -> A-layout ----
#pragma unroll
    for (int nt = 0; nt < 2; ++nt)
#pragma unroll
      for (int r = 0; r < 4; ++r)
        pw[(quad * 4 + r) * 40 + nt * 16 + n16] = f2bf(pv[nt][r]);

    // ---- PV: O[h][d] += P*V ; V-frag reads conflict-free via skew ----
    s16x8 pf = *(const s16x8*)(pw + n16 * 40 + quad * 8);
    const unsigned short* colq = (const unsigned short*)(kvw_b + quad * 2208);
#pragma unroll
    for (int dt = 0; dt < 8; ++dt) {
      const unsigned short* colp = colq + dt * 16 + n16;
      s16x8 vf;
#pragma unroll
      for (int j = 0; j < 8; ++j) vf[j] = (short)colp[j * 136];  // 272B row stride
      o_acc[dt] = __builtin_amdgcn_mfma_f32_16x16x32_bf16(pf, vf, o_acc[dt], 0, 0, 0);
    }
  }

  // ================= cross-wave combine (2 barriers total) =================
  if (n16 == 0) {
#pragma unroll
    for (int r = 0; r < 4; ++r) {
      m_lds[wave * 16 + quad * 4 + r] = m_r[r];
      l_lds[wave * 16 + quad * 4 + r] = l_r[r];
    }
  }
  __syncthreads();

  float myscale[4];
#pragma unroll
  for (int r = 0; r < 4; ++r) {
    int h = quad * 4 + r;
    float m0 = m_lds[h], m1 = m_lds[16 + h], m2 = m_lds[32 + h], m3 = m_lds[48 + h];
    float Mx = fmaxf(fmaxf(m0, m1), fmaxf(m2, m3));
    float Ls = l_lds[h] * exp2f(m0 - Mx) + l_lds[16 + h] * exp2f(m1 - Mx)
             + l_lds[32 + h] * exp2f(m2 - Mx) + l_lds[48 + h] * exp2f(m3 - Mx);
    myscale[r] = exp2f(m_r[r] - Mx);
    if (wave == 0 && n16 == 0) L_lds[h] = Ls;
  }
  // scaled partial O into LDS (overlaps kv region; all waves past key loop here)
#pragma unroll
  for (int dt = 0; dt < 8; ++dt)
#pragma unroll
    for (int r = 0; r < 4; ++r)
      o_all[(wave * 16 + quad * 4 + r) * 132 + dt * 16 + n16] = o_acc[dt][r] * myscale[r];
  __syncthreads();

  // final reduce over 4 waves + normalize; coalesced store
  float* outp = outg + (size_t)s * (N_HEADS * D_HEAD);
#pragma unroll
  for (int i = 0; i < 8; ++i) {
    int e = i * 256 + tid;           // 0..2047
    int h = e >> 7, d = e & 127;
    float acc = o_all[(0 * 16 + h) * 132 + d] + o_all[(1 * 16 + h) * 132 + d]
              + o_all[(2 * 16 + h) * 132 + d] + o_all[(3 * 16 + h) * 132 + d];
    outp[e] = acc / L_lds[h];
  }
}

extern "C" void kernel_launch(void* const* d_in, const int* in_sizes, int n_in,
                              void* d_out, int out_size, void* d_ws, size_t ws_size,
                              hipStream_t stream) {
  const float* q    = (const float*)d_in[0];
  const float* kv   = (const float*)d_in[1];
  const int*   topk = (const int*)d_in[2];
  float*       out  = (float*)d_out;
  unsigned short* kvb = (unsigned short*)d_ws;   // 8192*128*2 = 2 MB scratch

  kv_cvt_bf16<<<dim3(512), dim3(256), 0, stream>>>(kv, kvb);
  g2core_sparse_attn<<<dim3(S_LEN), dim3(256), 0, stream>>>(q, kvb, topk, out);
}

// Round 3
// 111.158 us; speedup vs baseline: 1.6008x; 1.0700x over previous
//
#include <hip/hip_runtime.h>
#include <stdint.h>

// Sparse top-k attention, B=1 S=2048 H=16 D=128 N_KV=8192 K=512.
// R3: no-max softmax (bounded scores; l via 9th ones-column MFMA),
// register-staged prefetched gather (QK B-frags straight from the gather
// loads), LDS only for the V tile (skewed, conflict-free column reads) and
// the P transpose. One block per query position; 4 waves x 128 private keys;
// zero barriers in the key loop.

typedef float  f32x4 __attribute__((ext_vector_type(4)));
typedef short  s16x8 __attribute__((ext_vector_type(8)));

#define S_LEN   2048
#define N_HEADS 16
#define D_HEAD  128
#define TOPK    512

// LDS map (bytes):
//  [0,35200)       V tiles: wave w at w*8800; row r at (r>>3)*2208+(r&7)*272
//                  (16B-aligned rows; V column reads conflict-free)
//                  (post-loop: wave-private O staging [16][132] f32 = 8448B,
//                   inside the same wave's 8800B region -> no cross-wave hazard)
//  [35200,40320)   p tiles: wave w at +w*1280, 16 rows x 40 ushort
//  [40320,40576)   lsum [4][16] f32
#define KV_WAVE  8800
#define P_BASE   35200
#define P_WAVE   1280
#define LSUM_BASE 40320
#define SMEM_BYTES 40576
#define KVROW(r) ((((r) >> 3) * 2208) + (((r) & 7) * 272))

// fp32 -> bf16 round-nearest-even
__device__ __forceinline__ unsigned short f2bf(float f) {
  union { float f; unsigned u; } v; v.f = f;
  return (unsigned short)((v.u + 0x7fffu + ((v.u >> 16) & 1u)) >> 16);
}

__global__ void __launch_bounds__(256) kv_cvt_bf16(
    const float* __restrict__ kv, unsigned short* __restrict__ o) {
  int i = (blockIdx.x * 256 + threadIdx.x) * 8;   // 8192*128 = 1M elems, grid 512
  float4 a = *(const float4*)(kv + i);
  float4 b = *(const float4*)(kv + i + 4);
  uint4 p;
  p.x = (unsigned)f2bf(a.x) | ((unsigned)f2bf(a.y) << 16);
  p.y = (unsigned)f2bf(a.z) | ((unsigned)f2bf(a.w) << 16);
  p.z = (unsigned)f2bf(b.x) | ((unsigned)f2bf(b.y) << 16);
  p.w = (unsigned)f2bf(b.z) | ((unsigned)f2bf(b.w) << 16);
  *(uint4*)(o + i) = p;
}

__global__ void __launch_bounds__(256, 3) g2core_sparse_attn(
    const float* __restrict__ qg, const unsigned short* __restrict__ kvb,
    const int* __restrict__ tkg, float* __restrict__ outg) {
  __shared__ __align__(16) char smem[SMEM_BYTES];
  unsigned short* p_all = (unsigned short*)(smem + P_BASE);
  float*          lsum  = (float*)(smem + LSUM_BASE);

  const int s    = blockIdx.x;
  const int tid  = threadIdx.x;
  const int wave = __builtin_amdgcn_readfirstlane(tid >> 6);
  const int lane = tid & 63;
  const int quad = lane >> 4;   // 0..3
  const int n16  = lane & 15;   // 0..15

  char*           kvw_b = smem + wave * KV_WAVE;
  unsigned short* pw    = p_all + wave * (P_WAVE / 2);

  // fold 1/sqrt(128) * log2(e) into Q; softmax runs unnormalized in exp2 domain
  const float QSCALE = 0.08838834764831845f * 1.4426950408889634f;

  // ---- Q A-frags in registers: A[m=n16(head)][k=32c+8*quad+j] ----
  s16x8 qf[4];
  {
    const float* qrow = qg + ((size_t)s * N_HEADS + n16) * D_HEAD;
#pragma unroll
    for (int c = 0; c < 4; ++c) {
      const float* p0 = qrow + c * 32 + quad * 8;
      float4 a = *(const float4*)(p0);
      float4 b = *(const float4*)(p0 + 4);
      s16x8 f;
      f[0] = (short)f2bf(a.x * QSCALE); f[1] = (short)f2bf(a.y * QSCALE);
      f[2] = (short)f2bf(a.z * QSCALE); f[3] = (short)f2bf(a.w * QSCALE);
      f[4] = (short)f2bf(b.x * QSCALE); f[5] = (short)f2bf(b.y * QSCALE);
      f[6] = (short)f2bf(b.z * QSCALE); f[7] = (short)f2bf(b.w * QSCALE);
      qf[c] = f;
    }
  }

  // ones-column B-frag for the l-sum MFMA: B[k][0]=1, B[k][n>0]=0
  s16x8 ones_f;
#pragma unroll
  for (int j = 0; j < 8; ++j) ones_f[j] = (n16 == 0) ? (short)0x3F80 : (short)0;

  f32x4 o_acc[9];   // [0..7]=O d-tiles, [8]=l in col 0
#pragma unroll
  for (int t = 0; t < 9; ++t) o_acc[t] = (f32x4){0.f, 0.f, 0.f, 0.f};

  // ---- prefetch all key indices for this wave: idxv[t*2+nt] = tk[t*32+nt*16+n16]
  const int* tk = tkg + (size_t)s * TOPK + wave * 128;
  int idxv[8];
#pragma unroll
  for (int i = 0; i < 8; ++i) idxv[i] = tk[i * 16 + n16];

  // ---- register staging: kst[buf][nt*4+c] = K[tk[nt*16+n16]][c*32+quad*8 ..+7]
  s16x8 kst[2][8];
#define STAGE(T, B)                                                          \
  {                                                                          \
    _Pragma("unroll") for (int nt = 0; nt < 2; ++nt) {                       \
      int ki = idxv[(T) * 2 + nt];                                           \
      ki = ki < 0 ? 0 : ki;                                                  \
      const char* rp = (const char*)kvb + ki * 256 + quad * 16;              \
      _Pragma("unroll") for (int c = 0; c < 4; ++c)                          \
          kst[B][nt * 4 + c] = *(const s16x8*)(rp + c * 64);                 \
    }                                                                        \
  }

  STAGE(0, 0)

  // ================= key loop: 4 tiles x 32 keys, wave-private =================
#pragma unroll
  for (int t = 0; t < 4; ++t) {
    const int b = t & 1;
    if (t < 3) STAGE(t + 1, b ^ 1)          // prefetch next tile (vmcnt overlap)

    // ---- stage V tile into LDS (8 ds_write_b128, rows 16B-aligned) ----
#pragma unroll
    for (int nt = 0; nt < 2; ++nt) {
      char* wp = kvw_b + KVROW(nt * 16 + n16) + quad * 16;
#pragma unroll
      for (int c = 0; c < 4; ++c)
        *(s16x8*)(wp + c * 64) = kst[b][nt * 4 + c];
    }

    // ---- QK straight from staged regs; p = exp2(s + bias), no max ----
#pragma unroll
    for (int nt = 0; nt < 2; ++nt) {
      f32x4 sa = (f32x4){0.f, 0.f, 0.f, 0.f};
#pragma unroll
      for (int c = 0; c < 4; ++c)
        sa = __builtin_amdgcn_mfma_f32_16x16x32_bf16(qf[c], kst[b][nt * 4 + c], sa, 0, 0, 0);
      float bias = (idxv[t * 2 + nt] < 0) ? -30000.0f : 0.0f;
#pragma unroll
      for (int r = 0; r < 4; ++r)
        pw[(quad * 4 + r) * 40 + nt * 16 + n16] = f2bf(exp2f(sa[r] + bias));
    }

    // ---- PV: A-frag from P transpose, V B-frags from skewed LDS ----
    s16x8 pf = *(const s16x8*)(pw + n16 * 40 + quad * 8);
    const unsigned short* colq = (const unsigned short*)(kvw_b + quad * 2208);
#pragma unroll
    for (int dt = 0; dt < 8; ++dt) {
      const unsigned short* colp = colq + dt * 16 + n16;
      s16x8 vf;
#pragma unroll
      for (int j = 0; j < 8; ++j) vf[j] = (short)colp[j * 136];  // 272B row stride
      o_acc[dt] = __builtin_amdgcn_mfma_f32_16x16x32_bf16(pf, vf, o_acc[dt], 0, 0, 0);
    }
    o_acc[8] = __builtin_amdgcn_mfma_f32_16x16x32_bf16(pf, ones_f, o_acc[8], 0, 0, 0);
  }
#undef STAGE

  // ================= cross-wave combine (plain sum; 1 barrier) =================
  float* ow = (float*)kvw_b;   // wave-private O staging inside own V region
#pragma unroll
  for (int dt = 0; dt < 8; ++dt)
#pragma unroll
    for (int r = 0; r < 4; ++r)
      ow[(quad * 4 + r) * 132 + dt * 16 + n16] = o_acc[dt][r];
  if (n16 == 0) {
#pragma unroll
    for (int r = 0; r < 4; ++r) lsum[wave * 16 + quad * 4 + r] = o_acc[8][r];
  }
  __syncthreads();

  float* outp = outg + (size_t)s * (N_HEADS * D_HEAD);
#pragma unroll
  for (int i = 0; i < 8; ++i) {
    int e = i * 256 + tid;           // 0..2047
    int h = e >> 7, d = e & 127;
    float acc = ((const float*)(smem + 0 * KV_WAVE))[h * 132 + d]
              + ((const float*)(smem + 1 * KV_WAVE))[h * 132 + d]
              + ((const float*)(smem + 2 * KV_WAVE))[h * 132 + d]
              + ((const float*)(smem + 3 * KV_WAVE))[h * 132 + d];
    float ls = lsum[h] + lsum[16 + h] + lsum[32 + h] + lsum[48 + h];
    outp[e] = acc / ls;
  }
}

extern "C" void kernel_launch(void* const* d_in, const int* in_sizes, int n_in,
                              void* d_out, int out_size, void* d_ws, size_t ws_size,
                              hipStream_t stream) {
  const float* q    = (const float*)d_in[0];
  const float* kv   = (const float*)d_in[1];
  const int*   topk = (const int*)d_in[2];
  float*       out  = (float*)d_out;
  unsigned short* kvb = (unsigned short*)d_ws;   // 8192*128*2 = 2 MB scratch

  kv_cvt_bf16<<<dim3(512), dim3(256), 0, stream>>>(kv, kvb);
  g2core_sparse_attn<<<dim3(S_LEN), dim3(256), 0, stream>>>(q, kvb, topk, out);
}